// Round 9
// baseline (543.129 us; speedup 1.0000x reference)
//
#include <hip/hip_runtime.h>
#include <math.h>

// Problem constants
#define BROWS 16384
#define N0    2048
#define NCLS  12
#define NCLU  24
#define NDIM  4
#define NCOL  348          // 12 + 288 + 48
#define NPAD  384          // padded fused-column count (24 col-tiles of 16)
#define NTILE 24           // NPAD/16

// Output offsets (floats): y0 [B,12] | y1_sel [B,24] | y2_sel [B,4] | Plc [B,24,12]
#define OUT0_OFF 0
#define OUT1_OFF (BROWS * NCLS)
#define OUT2_OFF (OUT1_OFF + BROWS * NCLU)
#define OUT3_OFF (OUT2_OFF + BROWS * NDIM)

typedef __attribute__((ext_vector_type(8))) short bf16x8;
typedef __attribute__((ext_vector_type(4))) float f32x4;
typedef unsigned short ushort_t;

// ---------------------------------------------------------------------------
// bf16 helpers — RNE split (bit-identical to the passing numerics)
// ---------------------------------------------------------------------------
__device__ __forceinline__ unsigned short f2bf(float f) {   // RNE
    unsigned u = __float_as_uint(f);
    u += 0x7fffu + ((u >> 16) & 1u);
    return (unsigned short)(u >> 16);
}
__device__ __forceinline__ float bf2f(unsigned short h) {
    return __uint_as_float(((unsigned)h) << 16);
}

// Packed-HW cvt: v_cvt_pk_bf16_f32 is RNE — bit-identical to the integer
// split, ~3x fewer VALU ops. No builtin on gfx950 -> inline asm.
__device__ __forceinline__ void cvt8pk(float4 a, float4 b, bf16x8& h, bf16x8& l) {
    unsigned h0, h1, h2, h3;
    asm("v_cvt_pk_bf16_f32 %0, %1, %2" : "=v"(h0) : "v"(a.x), "v"(a.y));
    asm("v_cvt_pk_bf16_f32 %0, %1, %2" : "=v"(h1) : "v"(a.z), "v"(a.w));
    asm("v_cvt_pk_bf16_f32 %0, %1, %2" : "=v"(h2) : "v"(b.x), "v"(b.y));
    asm("v_cvt_pk_bf16_f32 %0, %1, %2" : "=v"(h3) : "v"(b.z), "v"(b.w));
    float r0 = a.x - __uint_as_float(h0 << 16);
    float r1 = a.y - __uint_as_float(h0 & 0xffff0000u);
    float r2 = a.z - __uint_as_float(h1 << 16);
    float r3 = a.w - __uint_as_float(h1 & 0xffff0000u);
    float r4 = b.x - __uint_as_float(h2 << 16);
    float r5 = b.y - __uint_as_float(h2 & 0xffff0000u);
    float r6 = b.z - __uint_as_float(h3 << 16);
    float r7 = b.w - __uint_as_float(h3 & 0xffff0000u);
    unsigned l0, l1, l2, l3;
    asm("v_cvt_pk_bf16_f32 %0, %1, %2" : "=v"(l0) : "v"(r0), "v"(r1));
    asm("v_cvt_pk_bf16_f32 %0, %1, %2" : "=v"(l1) : "v"(r2), "v"(r3));
    asm("v_cvt_pk_bf16_f32 %0, %1, %2" : "=v"(l2) : "v"(r4), "v"(r5));
    asm("v_cvt_pk_bf16_f32 %0, %1, %2" : "=v"(l3) : "v"(r6), "v"(r7));
    union Pack { unsigned u[4]; bf16x8 v; };
    Pack H; H.u[0] = h0; H.u[1] = h1; H.u[2] = h2; H.u[3] = h3;
    Pack L; L.u[0] = l0; L.u[1] = l1; L.u[2] = l2; L.u[3] = l3;
    h = H.v;
    l = L.v;
}

__device__ __forceinline__ void load_lds16(const void* g, void* l) {
    __builtin_amdgcn_global_load_lds((const __attribute__((address_space(1))) void*)g,
                                     (__attribute__((address_space(3))) void*)l, 16, 0, 0);
}

__device__ __forceinline__ float fused_w(const float* __restrict__ W_fc,
                                         const float* __restrict__ W_bin,
                                         const float* __restrict__ W_res,
                                         int col, int d) {
    float w = 0.0f;
    if (col < NCLS) {
        w = W_fc[d * NCLS + col];
    } else if (col < 12 + NCLU * NCLS) {
        int jj = col - 12;
        int k = jj / NCLS, c = jj - k * NCLS;
        w = W_bin[((size_t)c * N0 + d) * NCLU + k];
    } else if (col < NCOL) {
        int jj = col - 300;
        int n = jj / NCLS, c = jj - n * NCLS;
        w = W_res[((size_t)c * N0 + d) * NDIM + n];
    }
    return w;
}

// ---------------------------------------------------------------------------
// Kernel 1: repack fused weights straight into MFMA-fragment streaming order.
// ---------------------------------------------------------------------------
__global__ void jcp_repack3(const float* __restrict__ W_fc, const float* __restrict__ b_fc,
                            const float* __restrict__ W_bin, const float* __restrict__ b_bin,
                            const float* __restrict__ W_res, const float* __restrict__ b_res,
                            ushort_t* __restrict__ Bph, ushort_t* __restrict__ Bpl,
                            float* __restrict__ bias) {
    int t = blockIdx.x * 256 + threadIdx.x;          // 0 .. 98303
    if (t >= NTILE * 64 * 64) return;
    const int lane = t & 63;
    const int kb   = (t >> 6) & 63;
    const int J    = t >> 12;
    const int col  = J * 16 + (lane & 15);
    const int k0   = kb * 32 + (lane >> 4) * 8;

    bf16x8 h, l;
    #pragma unroll
    for (int i = 0; i < 8; ++i) {
        float w = fused_w(W_fc, W_bin, W_res, col, k0 + i);
        unsigned short hi = f2bf(w);
        h[i] = (short)hi;
        l[i] = (short)f2bf(w - bf2f(hi));
    }
    *(bf16x8*)(Bph + (size_t)t * 8) = h;
    *(bf16x8*)(Bpl + (size_t)t * 8) = l;

    if (t < NPAD) {
        int jb = t;
        float bv = 0.0f;
        if (jb < NCLS) {
            bv = b_fc[jb];
        } else if (jb < 12 + NCLU * NCLS) {
            int jj = jb - 12;
            int k = jj / NCLS, c = jj - k * NCLS;
            bv = b_bin[c * NCLU + k];
        } else if (jb < NCOL) {
            int jj = jb - 300;
            int n = jj / NCLS, c = jj - n * NCLS;
            bv = b_res[c * NDIM + n];
        }
        bias[jb] = bv;
    }
}

// ---------------------------------------------------------------------------
// Kernel 2: split-bf16 MFMA GEMM v13 — gemm12 body + K-split for 2x TLP at
//   CONSTANT per-barrier density (the untested quadrant after R6/R8).
//   Grid 1024 = 128 row-panels x 4 col-blocks x 2 K-halves -> 4 blocks/CU.
//   Each block: 32 iters over its K half, tile 128x96, 36 MFMA/iter/wave.
//   LDS 32 KB (x only, dbuf 2x16KB); B direct global->regs, double-buffered.
//   ks=0 writes Y0 (with bias), ks=1 writes Y1; head sums them (deterministic,
//   no atomics). fp32 regrouping (p0+bias)+p1 is ~1e-7 — far below the
//   0.0156 bf16-split error floor.
// ---------------------------------------------------------------------------
#define GBODY(CUR, NXT, PBUF, RBUF, IT)                                        \
    {                                                                          \
        _Pragma("unroll")                                                      \
        for (int j = 0; j < 3; ++j) {                                          \
            bh[NXT][j] = *(const bf16x8*)(pBh + Jt3[j] + ((IT) + 1) * 512);    \
            bl[NXT][j] = *(const bf16x8*)(pBl + Jt3[j] + ((IT) + 1) * 512);    \
        }                                                                      \
        __builtin_amdgcn_sched_barrier(0);                                     \
        _Pragma("unroll")                                                      \
        for (int n = 0; n < 4; ++n)                                            \
            load_lds16(gx + n * 65536 + ((IT) + 2) * 32,                       \
                       &Lx[(PBUF) * 4096 + n * 1024 + tid * 4]);               \
        __builtin_amdgcn_sched_barrier(0);                                     \
        __builtin_amdgcn_s_setprio(1);                                         \
        _Pragma("unroll")                                                      \
        for (int j = 0; j < 3; ++j) {                                          \
            _Pragma("unroll")                                                  \
            for (int rt = 0; rt < 4; ++rt) {                                   \
                acc[rt][j] = __builtin_amdgcn_mfma_f32_16x16x32_bf16(          \
                    Ah[CUR][rt], bh[CUR][j], acc[rt][j], 0, 0, 0);             \
                acc[rt][j] = __builtin_amdgcn_mfma_f32_16x16x32_bf16(          \
                    Al[CUR][rt], bh[CUR][j], acc[rt][j], 0, 0, 0);             \
                acc[rt][j] = __builtin_amdgcn_mfma_f32_16x16x32_bf16(          \
                    Ah[CUR][rt], bl[CUR][j], acc[rt][j], 0, 0, 0);             \
            }                                                                  \
        }                                                                      \
        __builtin_amdgcn_s_setprio(0);                                         \
        asm volatile("s_waitcnt vmcnt(10)" ::: "memory");                      \
        asm volatile("s_barrier" ::: "memory");                                \
        __builtin_amdgcn_sched_barrier(0);                                     \
        {                                                                      \
            const float* lx = &Lx[(RBUF) * 4096];                              \
            _Pragma("unroll")                                                  \
            for (int rt = 0; rt < 4; ++rt) {                                   \
                const int ro = (rg * 64 + rt * 16 + l16) * 32;                 \
                fa4[rt] = *(const float4*)&lx[ro + o1];                        \
                fb4[rt] = *(const float4*)&lx[ro + o2];                        \
            }                                                                  \
            asm volatile("s_waitcnt lgkmcnt(0)" ::: "memory");                 \
            __builtin_amdgcn_sched_barrier(0);                                 \
            _Pragma("unroll")                                                  \
            for (int rt = 0; rt < 4; ++rt)                                     \
                cvt8pk(fa4[rt], fb4[rt], Ah[NXT][rt], Al[NXT][rt]);            \
        }                                                                      \
        asm volatile("s_waitcnt vmcnt(4)" ::: "memory");                       \
        __builtin_amdgcn_sched_barrier(0);                                     \
        asm volatile("s_barrier" ::: "memory");                                \
    }

__global__ __launch_bounds__(256, 4) void jcp_gemm13(const float* __restrict__ x,
                                                     const ushort_t* __restrict__ Bph,
                                                     const ushort_t* __restrict__ Bpl,
                                                     const float* __restrict__ bias,
                                                     float* __restrict__ Y0,
                                                     float* __restrict__ Y1) {
    __shared__ float Lx[2 * 4096];    // 2 bufs x 128 rows x 32 fp32 = 16 KB each

    const int tid  = threadIdx.x;
    const int wid  = tid >> 6;
    const int lane = tid & 63;
    const int quad = lane >> 4;
    const int l16  = lane & 15;
    const int rg   = wid & 1;            // row half of block (64 rows)
    const int cg   = wid >> 1;           // col half of block (48 cols)

    // XCD-bijective decode: 8 blocks per (xcd, row-panel): 4 col x 2 K-halves.
    const int g   = blockIdx.x;          // 0..1023, 1024 % 8 == 0 -> bijective
    const int xcd = g & 7;
    const int jj  = g >> 3;              // 0..127
    const int by  = xcd * 16 + (jj >> 3);   // 0..127 row-panel
    const int bx  = (jj >> 1) & 3;          // col-block 0..3
    const int ks  = jj & 1;                 // K half 0..1
    const int rbase = by * 128;
    const int jbase = bx * 96;

    // --- x DMA (raw fp32): base offset into this block's K half. ---
    const int r0 = tid >> 3;             // 0..31
    const int c0 = tid & 7;
    const int o0 = c0 ^ (r0 & 7);        // (r0+32n)&7 == r0&7
    const float* gx = x + (size_t)(rbase + r0) * N0 + ks * 1024 + o0 * 4;   // + it*32 ; inst n: +n*65536

    // --- B direct-load pointers, offset to this K half (kb = ks*32 + it). ---
    const ushort_t* pBh = Bph + (size_t)lane * 8 + (size_t)ks * 32 * 512;
    const ushort_t* pBl = Bpl + (size_t)lane * 8 + (size_t)ks * 32 * 512;
    int Jt3[3];
    #pragma unroll
    for (int j = 0; j < 3; ++j) Jt3[j] = (bx * 6 + cg * 3 + j) * 32768;

    // --- A fragment read offsets (floats), proven swizzled layout ---
    const int s  = l16 & 7;
    const int o1 = ((2 * quad) ^ s) * 4;
    const int o2 = o1 ^ 4;

    f32x4 acc[4][3];
    #pragma unroll
    for (int rt = 0; rt < 4; ++rt)
        #pragma unroll
        for (int j = 0; j < 3; ++j)
            acc[rt][j] = f32x4{0.f, 0.f, 0.f, 0.f};

    bf16x8 Ah[2][4], Al[2][4], bh[2][3], bl[2][3];
    float4 fa4[4], fb4[4];

    // Prologue: x(0)->buf0 [4], B(0)->set0 [6], x(1)->buf1 [4]  (14 in flight)
    #pragma unroll
    for (int n = 0; n < 4; ++n) load_lds16(gx + n * 65536, &Lx[n * 1024 + tid * 4]);
    __builtin_amdgcn_sched_barrier(0);
    #pragma unroll
    for (int j = 0; j < 3; ++j) {
        bh[0][j] = *(const bf16x8*)(pBh + Jt3[j]);
        bl[0][j] = *(const bf16x8*)(pBl + Jt3[j]);
    }
    __builtin_amdgcn_sched_barrier(0);
    #pragma unroll
    for (int n = 0; n < 4; ++n) load_lds16(gx + n * 65536 + 32, &Lx[4096 + n * 1024 + tid * 4]);
    __builtin_amdgcn_sched_barrier(0);
    asm volatile("s_waitcnt vmcnt(10)" ::: "memory");   // x(0) done (4 oldest)
    asm volatile("s_barrier" ::: "memory");
    __builtin_amdgcn_sched_barrier(0);
    {   // A(0) from buf0 -> set0
        const float* lx = &Lx[0];
        #pragma unroll
        for (int rt = 0; rt < 4; ++rt) {
            const int ro = (rg * 64 + rt * 16 + l16) * 32;
            fa4[rt] = *(const float4*)&lx[ro + o1];
            fb4[rt] = *(const float4*)&lx[ro + o2];
        }
        asm volatile("s_waitcnt lgkmcnt(0)" ::: "memory");
        __builtin_amdgcn_sched_barrier(0);
        #pragma unroll
        for (int rt = 0; rt < 4; ++rt) cvt8pk(fa4[rt], fb4[rt], Ah[0][rt], Al[0][rt]);
    }
    asm volatile("s_waitcnt vmcnt(4)" ::: "memory");    // B(0) regs landed
    __builtin_amdgcn_sched_barrier(0);
    asm volatile("s_barrier" ::: "memory");             // reads of buf0 done

    // Main loop: 30 bodies (0..29), 2x unrolled (literal indices everywhere).
    for (int it = 0; it < 30; it += 2) {
        GBODY(0, 1, 0, 1, it);
        GBODY(1, 0, 1, 0, it + 1);
    }

    // Peeled body(30): set0 holds frags(30); buf1 holds x(31); x(31) in flight.
    {
        #pragma unroll
        for (int j = 0; j < 3; ++j) {
            bh[1][j] = *(const bf16x8*)(pBh + Jt3[j] + 31 * 512);
            bl[1][j] = *(const bf16x8*)(pBl + Jt3[j] + 31 * 512);
        }
        __builtin_amdgcn_sched_barrier(0);
        __builtin_amdgcn_s_setprio(1);
        #pragma unroll
        for (int j = 0; j < 3; ++j)
            #pragma unroll
            for (int rt = 0; rt < 4; ++rt) {
                acc[rt][j] = __builtin_amdgcn_mfma_f32_16x16x32_bf16(Ah[0][rt], bh[0][j], acc[rt][j], 0, 0, 0);
                acc[rt][j] = __builtin_amdgcn_mfma_f32_16x16x32_bf16(Al[0][rt], bh[0][j], acc[rt][j], 0, 0, 0);
                acc[rt][j] = __builtin_amdgcn_mfma_f32_16x16x32_bf16(Ah[0][rt], bl[0][j], acc[rt][j], 0, 0, 0);
            }
        __builtin_amdgcn_s_setprio(0);
        asm volatile("s_waitcnt vmcnt(6)" ::: "memory");   // x(31) done
        asm volatile("s_barrier" ::: "memory");
        __builtin_amdgcn_sched_barrier(0);
        const float* lx = &Lx[4096];
        #pragma unroll
        for (int rt = 0; rt < 4; ++rt) {
            const int ro = (rg * 64 + rt * 16 + l16) * 32;
            fa4[rt] = *(const float4*)&lx[ro + o1];
            fb4[rt] = *(const float4*)&lx[ro + o2];
        }
        asm volatile("s_waitcnt lgkmcnt(0)" ::: "memory");
        __builtin_amdgcn_sched_barrier(0);
        #pragma unroll
        for (int rt = 0; rt < 4; ++rt) cvt8pk(fa4[rt], fb4[rt], Ah[1][rt], Al[1][rt]);
        asm volatile("s_waitcnt vmcnt(0)" ::: "memory");   // B(31) regs landed
        __builtin_amdgcn_sched_barrier(0);
        #pragma unroll
        for (int j = 0; j < 3; ++j)
            #pragma unroll
            for (int rt = 0; rt < 4; ++rt) {
                acc[rt][j] = __builtin_amdgcn_mfma_f32_16x16x32_bf16(Ah[1][rt], bh[1][j], acc[rt][j], 0, 0, 0);
                acc[rt][j] = __builtin_amdgcn_mfma_f32_16x16x32_bf16(Al[1][rt], bh[1][j], acc[rt][j], 0, 0, 0);
                acc[rt][j] = __builtin_amdgcn_mfma_f32_16x16x32_bf16(Ah[1][rt], bl[1][j], acc[rt][j], 0, 0, 0);
            }
    }

    // Epilogue: partial to Y0 (with bias) or Y1. C/D: col = lane&15, row = quad*4 + reg.
    float* Yp = ks ? Y1 : Y0;
    #pragma unroll
    for (int j = 0; j < 3; ++j) {
        const int col = jbase + cg * 48 + 16 * j + l16;
        const float bj = ks ? 0.0f : bias[col];
        #pragma unroll
        for (int rt = 0; rt < 4; ++rt) {
            float* yp = Yp + (size_t)(rbase + rg * 64 + rt * 16 + quad * 4) * NPAD + col;
            yp[0 * NPAD] = acc[rt][j][0] + bj;
            yp[1 * NPAD] = acc[rt][j][1] + bj;
            yp[2 * NPAD] = acc[rt][j][2] + bj;
            yp[3 * NPAD] = acc[rt][j][3] + bj;
        }
    }
}

// ---------------------------------------------------------------------------
// Kernel 3: head v5 — sums the two K-half partials while loading to LDS.
// ---------------------------------------------------------------------------
#define LROW 388   // padded LDS row stride (floats)

__global__ __launch_bounds__(256) void jcp_head5(const float* __restrict__ Y0,
                                                 const float* __restrict__ Y1,
                                                 float* __restrict__ out) {
    __shared__ float Ly[16 * LROW];
    const int tid = threadIdx.x;
    const int r0  = blockIdx.x * 16;

    #pragma unroll
    for (int jj = 0; jj < 6; ++jj) {
        int f = tid + jj * 256;
        int row = f / 96, c4 = f - row * 96;
        float4 a = *(const float4*)(Y0 + (size_t)(r0 + row) * NPAD + c4 * 4);
        float4 b = *(const float4*)(Y1 + (size_t)(r0 + row) * NPAD + c4 * 4);
        float4 v; v.x = a.x + b.x; v.y = a.y + b.y; v.z = a.z + b.z; v.w = a.w + b.w;
        *(float4*)&Ly[row * LROW + c4 * 4] = v;
    }
    __syncthreads();

    const int grp = tid >> 4;
    const int c   = tid & 15;
    const bool on = (c < NCLS);
    const int r   = r0 + grp;
    const float* y = &Ly[grp * LROW];

    float y0c = on ? y[c] : -INFINITY;
    float m0 = y0c;
    #pragma unroll
    for (int m = 8; m >= 1; m >>= 1) m0 = fmaxf(m0, __shfl_xor(m0, m, 16));
    float e0 = on ? expf(y0c - m0) : 0.0f;
    float s0 = e0;
    #pragma unroll
    for (int m = 8; m >= 1; m >>= 1) s0 += __shfl_xor(s0, m, 16);
    const float Pc = e0 / s0;

    float v[NCLU];
    float mc = -INFINITY;
    #pragma unroll
    for (int k = 0; k < NCLU; ++k) {
        v[k] = y[12 + k * NCLS + c];
        mc = fmaxf(mc, v[k]);
    }
    float ev[NCLU];
    float sc = 0.0f;
    #pragma unroll
    for (int k = 0; k < NCLU; ++k) { ev[k] = expf(v[k] - mc); sc += ev[k]; }
    const float rs = Pc / sc;

    float y2c[NDIM];
    #pragma unroll
    for (int n = 0; n < NDIM; ++n) y2c[n] = y[300 + n * NCLS + c];

    float best = -INFINITY;
    int bk = 0;
    float* lrow = &Ly[grp * LROW];
    #pragma unroll
    for (int k = 0; k < NCLU; ++k) {
        const float p = ev[k] * rs;
        if (on) lrow[k * NCLS + c] = p;
        if (p > best) { best = p; bk = k; }
    }
    int flat = bk * NCLS + c;
    if (!on) { best = -INFINITY; flat = 1 << 30; }

    #pragma unroll
    for (int m = 8; m >= 1; m >>= 1) {
        const float op = __shfl_xor(best, m, 16);
        const int   of = __shfl_xor(flat, m, 16);
        if (op > best || (op == best && of < flat)) { best = op; flat = of; }
    }
    const int ic = flat % NCLS;

    if (on) out[OUT0_OFF + (size_t)r * NCLS + c] = y0c;
    if (c == ic) {
        float* o1v = out + OUT1_OFF + (size_t)r * NCLU;
        #pragma unroll
        for (int k = 0; k < NCLU; ++k) o1v[k] = v[k];
        float* o2v = out + OUT2_OFF + (size_t)r * NDIM;
        #pragma unroll
        for (int n = 0; n < NDIM; ++n) o2v[n] = y2c[n];
    }

    __syncthreads();
    #pragma unroll
    for (int jj = 0; jj < 5; ++jj) {
        int f = tid + jj * 256;
        if (f < 1152) {
            int row = f / 72, c4 = f - row * 72;
            *(float4*)(out + OUT3_OFF + (size_t)(r0 + row) * (NCLU * NCLS) + c4 * 4) =
                *(float4*)&Ly[row * LROW + c4 * 4];
        }
    }
}

// ---------------------------------------------------------------------------
extern "C" void kernel_launch(void* const* d_in, const int* in_sizes, int n_in,
                              void* d_out, int out_size, void* d_ws, size_t ws_size,
                              hipStream_t stream) {
    const float* x     = (const float*)d_in[0];
    const float* W_fc  = (const float*)d_in[1];
    const float* b_fc  = (const float*)d_in[2];
    const float* W_bin = (const float*)d_in[3];
    const float* b_bin = (const float*)d_in[4];
    const float* W_res = (const float*)d_in[5];
    const float* b_res = (const float*)d_in[6];
    float* out = (float*)d_out;

    // ws layout (bytes): Bph 1.5MB | Bpl 1.5MB | bias 1.5KB | Y0 25.2MB | Y1 25.2MB
    ushort_t* Bph  = (ushort_t*)d_ws;                  // 24*64*64*8 bf16 = 1.5 MB
    ushort_t* Bpl  = Bph + NTILE * 64 * 64 * 8;        // 1.5 MB
    float*    bias = (float*)(Bpl + NTILE * 64 * 64 * 8);
    float*    Y0   = bias + NPAD;                      // 16384*384 fp32
    float*    Y1   = Y0 + (size_t)BROWS * NPAD;        // 16384*384 fp32

    jcp_repack3<<<384, 256, 0, stream>>>(W_fc, b_fc, W_bin, b_bin, W_res, b_res,
                                         Bph, Bpl, bias);
    jcp_gemm13<<<1024, 256, 0, stream>>>(x, Bph, Bpl, bias, Y0, Y1);
    jcp_head5<<<BROWS / 16, 256, 0, stream>>>(Y0, Y1, out);
}